// Round 1
// baseline (270.697 us; speedup 1.0000x reference)
//
#include <hip/hip_runtime.h>

// C = triu(A @ B), A,B upper-triangular fp32 4096x4096.
// Strategy: convert A -> bf16 row-major, B -> bf16 TRANSPOSED (Bt[n][k]=B[k][n])
// into d_ws, then block-triangular MFMA GEMM (only kb in [bi,bj] contributes).
// m97-style structure: 128x128 tile, BK=32, mfma_f32_16x16x32_bf16,
// global_load_lds width=16, 4 waves x (64x64 quadrant, 4x4 float4 acc).

#define N   4096
#define NB  32      // N / BM
#define BM  128
#define BK  32

typedef __attribute__((ext_vector_type(8))) __bf16 bf16x8;
typedef __attribute__((ext_vector_type(4))) float  floatx4;

typedef const __attribute__((address_space(1))) void* gas_ptr;
typedef __attribute__((address_space(3))) void*       las_ptr;

__device__ __forceinline__ unsigned short f32_to_bf16_rne(float f) {
    unsigned u = __builtin_bit_cast(unsigned, f);
    unsigned r = u + 0x7fffu + ((u >> 16) & 1u);
    return (unsigned short)(r >> 16);
}

// --- A: fp32 -> bf16, same layout (row-major, K contiguous) ---
__global__ void conv_a_kernel(const float* __restrict__ A,
                              unsigned short* __restrict__ Ab) {
    int idx = (blockIdx.x * 256 + threadIdx.x) * 4;
    const float4 v = *(const float4*)(A + idx);
    ushort4 o;
    o.x = f32_to_bf16_rne(v.x);
    o.y = f32_to_bf16_rne(v.y);
    o.z = f32_to_bf16_rne(v.z);
    o.w = f32_to_bf16_rne(v.w);
    *(ushort4*)(Ab + idx) = o;
}

// --- B: fp32 -> bf16 transposed (Bt[j][k] = B[k][j]), K contiguous ---
__global__ void conv_bt_kernel(const float* __restrict__ B,
                               unsigned short* __restrict__ Bt) {
    __shared__ float tile[32][33];   // +1 pad: no bank conflicts
    int j0 = blockIdx.x * 32;       // B column block
    int k0 = blockIdx.y * 32;       // B row block
    int tx = threadIdx.x;           // 0..31
    int ty = threadIdx.y;           // 0..7
    for (int i = 0; i < 32; i += 8)
        tile[ty + i][tx] = B[(size_t)(k0 + ty + i) * N + j0 + tx];
    __syncthreads();
    for (int i = 0; i < 32; i += 8)
        Bt[(size_t)(j0 + ty + i) * N + k0 + tx] = f32_to_bf16_rne(tile[tx][ty + i]);
}

// --- triangular-blocked bf16 MFMA GEMM ---
__global__ __launch_bounds__(256)
void trimm_kernel(const unsigned short* __restrict__ Ab,
                  const unsigned short* __restrict__ Bt,
                  float* __restrict__ C) {
    __shared__ unsigned short sA[BM * BK];   // [row][k] 128x32
    __shared__ unsigned short sB[BM * BK];   // [col][k] 128x32 (Bt rows)

    const int bj = blockIdx.x;   // output block col
    const int bi = blockIdx.y;   // output block row

    const int tid  = threadIdx.x;
    const int w    = tid >> 6;        // wave 0..3
    const int lane = tid & 63;
    const int quad = lane >> 4;       // 0..3
    const int l15  = lane & 15;

    const int m0 = (w >> 1) * 64;     // wave quadrant within 128x128
    const int n0 = (w & 1) * 64;
    const int row0 = bi * BM;
    const int col0 = bj * BM;

    floatx4 acc[4][4] = {};

    if (bj >= bi) {
        // Only K-blocks [bi, bj] contribute (A upper-tri x B upper-tri).
        const int ksteps = (bj - bi + 1) * (BM / BK);
        const int kbase  = bi * BM;

        // staging: 8 wave-chunks of 1KB per tile; wave w does chunks 2w, 2w+1
        const int srow = lane >> 2;        // 0..15 row within chunk
        const int skk  = (lane & 3) * 8;   // k element offset (8 bf16 = 16B)

        for (int s = 0; s < ksteps; ++s) {
            const int k0 = kbase + s * BK;
            for (int c = 0; c < 2; ++c) {
                const int q = w * 2 + c;           // chunk id: rows q*16..q*16+15
                const int r = q * 16 + srow;
                const unsigned short* gA = Ab + (size_t)(row0 + r) * N + k0 + skk;
                const unsigned short* gB = Bt + (size_t)(col0 + r) * N + k0 + skk;
                __builtin_amdgcn_global_load_lds((gas_ptr)gA, (las_ptr)&sA[q * 512], 16, 0, 0);
                __builtin_amdgcn_global_load_lds((gas_ptr)gB, (las_ptr)&sB[q * 512], 16, 0, 0);
            }
            __syncthreads();

            bf16x8 af[4], bfr[4];
            #pragma unroll
            for (int t = 0; t < 4; ++t) {
                af[t]  = *(const bf16x8*)&sA[(m0 + t * 16 + l15) * BK + quad * 8];
                bfr[t] = *(const bf16x8*)&sB[(n0 + t * 16 + l15) * BK + quad * 8];
            }
            #pragma unroll
            for (int tm = 0; tm < 4; ++tm)
                #pragma unroll
                for (int tn = 0; tn < 4; ++tn)
                    acc[tm][tn] = __builtin_amdgcn_mfma_f32_16x16x32_bf16(
                        af[tm], bfr[tn], acc[tm][tn], 0, 0, 0);
            __syncthreads();
        }
    }

    // Epilogue: C/D layout col=lane&15, row=quad*4+r. Mask to triu
    // (off-diagonal upper blocks: always col>=row; lower blocks: acc==0).
    #pragma unroll
    for (int tm = 0; tm < 4; ++tm) {
        const int grow_base = row0 + m0 + tm * 16 + quad * 4;
        #pragma unroll
        for (int tn = 0; tn < 4; ++tn) {
            const int gcol = col0 + n0 + tn * 16 + l15;
            #pragma unroll
            for (int r = 0; r < 4; ++r) {
                const int grow = grow_base + r;
                const float v = (gcol >= grow) ? acc[tm][tn][r] : 0.0f;
                C[(size_t)grow * N + gcol] = v;
            }
        }
    }
}

extern "C" void kernel_launch(void* const* d_in, const int* in_sizes, int n_in,
                              void* d_out, int out_size, void* d_ws, size_t ws_size,
                              hipStream_t stream) {
    const float* A = (const float*)d_in[0];
    const float* B = (const float*)d_in[1];
    float* C = (float*)d_out;

    // workspace: A_bf16 (32 MiB) | Bt_bf16 (32 MiB)
    unsigned short* Ab = (unsigned short*)d_ws;
    unsigned short* Bt = Ab + (size_t)N * N;

    conv_a_kernel<<<dim3(N * N / 1024), dim3(256), 0, stream>>>(A, Ab);
    conv_bt_kernel<<<dim3(N / 32, N / 32), dim3(32, 8), 0, stream>>>(B, Bt);
    trimm_kernel<<<dim3(NB, NB), dim3(256), 0, stream>>>(Ab, Bt, C);
}

// Round 2
// 251.521 us; speedup vs baseline: 1.0762x; 1.0762x over previous
//
#include <hip/hip_runtime.h>

// C = triu(A @ B), A,B upper-triangular fp32 4096x4096.
// R2: (1) split-K balanced 1D grid for the MFMA GEMM (CH=8 K-blocks/chunk,
//     1000 wgs, fp32 atomicAdd onto memset-zeroed C for multi-chunk tiles),
// (2) vectorized LDS-transpose conv for Bt, (3) skip never-read tri blocks.

#define N   4096
#define NB  32      // N / BM
#define BM  128
#define BK  32
#define CH  8       // K-blocks (128 wide) per chunk
#define NWG 1000    // sum over d of (NB-d)*ceil((d+1)/CH)  [NB=32, CH=8]

typedef __attribute__((ext_vector_type(8))) __bf16 bf16x8;
typedef __attribute__((ext_vector_type(4))) float  floatx4;
typedef __attribute__((ext_vector_type(8))) unsigned short ushort8;

typedef const __attribute__((address_space(1))) void* gas_ptr;
typedef __attribute__((address_space(3))) void*       las_ptr;

__device__ __forceinline__ unsigned short f32_to_bf16_rne(float f) {
    unsigned u = __builtin_bit_cast(unsigned, f);
    unsigned r = u + 0x7fffu + ((u >> 16) & 1u);
    return (unsigned short)(r >> 16);
}

// --- A: fp32 -> bf16 row-major; skip strictly-lower 128-blocks (never read) ---
__global__ void conv_a_kernel(const float* __restrict__ A,
                              unsigned short* __restrict__ Ab) {
    const int bid = blockIdx.x;
    const int row = bid >> 2;            // one quarter-row (1024 elems) per wg
    const int k0  = (bid & 3) * 1024;
    const int rb  = row >> 7;            // 128-block row
    if (((k0 >> 7) + 8) <= rb) return;   // all 8 k-blocks strictly below diag
    const int idx = row * N + k0 + threadIdx.x * 4;
    const float4 v = *(const float4*)(A + idx);
    ushort4 o;
    o.x = f32_to_bf16_rne(v.x);
    o.y = f32_to_bf16_rne(v.y);
    o.z = f32_to_bf16_rne(v.z);
    o.w = f32_to_bf16_rne(v.w);
    *(ushort4*)(Ab + idx) = o;
}

// --- B: fp32 -> bf16 transposed (Bt[j][k] = B[k][j]); 64x64 LDS transpose.
//     Skip Bt 128-blocks with kb128 > jb128 (never read). ---
__global__ void conv_bt_kernel(const float* __restrict__ B,
                               unsigned short* __restrict__ Bt) {
    __shared__ float tile[64][65];
    const int jb = blockIdx.x;           // Bt row block (B column block), 64-wide
    const int kb = blockIdx.y;           // Bt col block (B row block), 64-wide
    if ((kb >> 1) > (jb >> 1)) return;
    const int j0 = jb * 64, k0 = kb * 64;
    const int t  = threadIdx.x;          // 0..255
    {
        const int kl = t >> 2;           // row of B within tile
        const int j4 = (t & 3) * 16;     // 16 consecutive j per thread
        const float* src = B + (size_t)(k0 + kl) * N + j0 + j4;
        const float4 v0 = ((const float4*)src)[0];
        const float4 v1 = ((const float4*)src)[1];
        const float4 v2 = ((const float4*)src)[2];
        const float4 v3 = ((const float4*)src)[3];
        float* dst = &tile[kl][j4];
        dst[0]=v0.x; dst[1]=v0.y; dst[2]=v0.z; dst[3]=v0.w;
        dst[4]=v1.x; dst[5]=v1.y; dst[6]=v1.z; dst[7]=v1.w;
        dst[8]=v2.x; dst[9]=v2.y; dst[10]=v2.z; dst[11]=v2.w;
        dst[12]=v3.x; dst[13]=v3.y; dst[14]=v3.z; dst[15]=v3.w;
    }
    __syncthreads();
    {
        const int jl = t >> 2;           // row of Bt within tile
        const int k4 = (t & 3) * 16;     // 16 consecutive k per thread
        ushort8 o0, o1;
        #pragma unroll
        for (int i = 0; i < 8; ++i) o0[i] = f32_to_bf16_rne(tile[k4 + i][jl]);
        #pragma unroll
        for (int i = 0; i < 8; ++i) o1[i] = f32_to_bf16_rne(tile[k4 + 8 + i][jl]);
        unsigned short* dst = Bt + (size_t)(j0 + jl) * N + k0 + k4;
        ((ushort8*)dst)[0] = o0;
        ((ushort8*)dst)[1] = o1;
    }
}

// --- split-K triangular-blocked bf16 MFMA GEMM ---
__global__ __launch_bounds__(256)
void trimm_kernel(const unsigned short* __restrict__ Ab,
                  const unsigned short* __restrict__ Bt,
                  float* __restrict__ C) {
    __shared__ unsigned short sA[BM * BK];   // [row][k] 128x32
    __shared__ unsigned short sB[BM * BK];   // [col][k] 128x32 (Bt rows)

    // ---- decode blockIdx -> (tile bi,bj ; K-chunk) ; expensive diagonals first
    int rem = blockIdx.x;
    int d = 0, per = 1;
    for (int dd = NB - 1; dd >= 0; --dd) {
        const int p   = (dd + CH) / CH;          // ceil((dd+1)/CH)
        const int cnt = (NB - dd) * p;
        if (rem < cnt) { d = dd; per = p; break; }
        rem -= cnt;
    }
    const int tile  = rem / per;
    const int chunk = rem - tile * per;
    const int bi = tile, bj = tile + d;
    const int c    = d + 1;                      // tile cost in K-blocks
    const int base = c / per, extra = c - base * per;
    const int kb0  = bi + chunk * base + (chunk < extra ? chunk : extra);
    const int len  = base + (chunk < extra ? 1 : 0);

    const int tid  = threadIdx.x;
    const int w    = tid >> 6;        // wave 0..3
    const int lane = tid & 63;
    const int quad = lane >> 4;       // 0..3
    const int l15  = lane & 15;

    const int m0 = (w >> 1) * 64;     // wave quadrant within 128x128
    const int n0 = (w & 1) * 64;
    const int row0 = bi * BM;
    const int col0 = bj * BM;

    floatx4 acc[4][4] = {};

    // staging: 8 wave-chunks of 1KB per tile; wave w does chunks 2w, 2w+1
    const int srow = lane >> 2;        // 0..15 row within chunk
    const int skk  = (lane & 3) * 8;   // k element offset (8 bf16 = 16B)

    const int s0 = kb0 * 4;            // BK-steps
    const int ns = len * 4;
    for (int s = 0; s < ns; ++s) {
        const int k0 = (s0 + s) * BK;
        for (int cc = 0; cc < 2; ++cc) {
            const int q = w * 2 + cc;
            const int r = q * 16 + srow;
            const unsigned short* gA = Ab + (size_t)(row0 + r) * N + k0 + skk;
            const unsigned short* gB = Bt + (size_t)(col0 + r) * N + k0 + skk;
            __builtin_amdgcn_global_load_lds((gas_ptr)gA, (las_ptr)&sA[q * 512], 16, 0, 0);
            __builtin_amdgcn_global_load_lds((gas_ptr)gB, (las_ptr)&sB[q * 512], 16, 0, 0);
        }
        __syncthreads();

        bf16x8 af[4], bfr[4];
        #pragma unroll
        for (int t = 0; t < 4; ++t) {
            af[t]  = *(const bf16x8*)&sA[(m0 + t * 16 + l15) * BK + quad * 8];
            bfr[t] = *(const bf16x8*)&sB[(n0 + t * 16 + l15) * BK + quad * 8];
        }
        #pragma unroll
        for (int tm = 0; tm < 4; ++tm)
            #pragma unroll
            for (int tn = 0; tn < 4; ++tn)
                acc[tm][tn] = __builtin_amdgcn_mfma_f32_16x16x32_bf16(
                    af[tm], bfr[tn], acc[tm][tn], 0, 0, 0);
        __syncthreads();
    }

    // ---- epilogue. C/D layout: col=lane&15, row=quad*4+r.
    // per>1  -> tile is strictly upper (d>=8): unconditional atomicAdd.
    // per==1 -> sole writer: plain store; mask triu only on diagonal (d==0).
    #pragma unroll
    for (int tm = 0; tm < 4; ++tm) {
        const int grow_base = row0 + m0 + tm * 16 + quad * 4;
        #pragma unroll
        for (int tn = 0; tn < 4; ++tn) {
            const int gcol = col0 + n0 + tn * 16 + l15;
            #pragma unroll
            for (int r = 0; r < 4; ++r) {
                const int grow = grow_base + r;
                float* p = C + (size_t)grow * N + gcol;
                const float v = acc[tm][tn][r];
                if (per > 1) {
                    atomicAdd(p, v);
                } else if (d != 0) {
                    *p = v;
                } else if (gcol >= grow) {
                    *p = v;
                }
            }
        }
    }
}

extern "C" void kernel_launch(void* const* d_in, const int* in_sizes, int n_in,
                              void* d_out, int out_size, void* d_ws, size_t ws_size,
                              hipStream_t stream) {
    const float* A = (const float*)d_in[0];
    const float* B = (const float*)d_in[1];
    float* C = (float*)d_out;

    // workspace: A_bf16 (32 MiB) | Bt_bf16 (32 MiB)
    unsigned short* Ab = (unsigned short*)d_ws;
    unsigned short* Bt = Ab + (size_t)N * N;

    hipMemsetAsync(d_out, 0, (size_t)N * N * sizeof(float), stream);
    conv_a_kernel<<<dim3(N * 4), dim3(256), 0, stream>>>(A, Ab);
    conv_bt_kernel<<<dim3(N / 64, N / 64), dim3(256), 0, stream>>>(B, Bt);
    trimm_kernel<<<dim3(NWG), dim3(256), 0, stream>>>(Ab, Bt, C);
}

// Round 3
// 243.761 us; speedup vs baseline: 1.1105x; 1.0318x over previous
//
#include <hip/hip_runtime.h>

// C = triu(A @ B), A,B upper-triangular fp32 4096x4096.
// R3: trimm processes TWO BK=32 steps per barrier pair (double LDS buffer set,
// 32KB) -> half the vmcnt(0)+barrier drains, 8 loads in flight per wave.
// Grid/decode/epilogue identical to R2 (split-K CH=8, 1000 wgs, atomics).

#define N   4096
#define NB  32      // N / BM
#define BM  128
#define BK  32
#define CH  8       // K-blocks (128 wide) per chunk
#define NWG 1000    // sum over d of (NB-d)*ceil((d+1)/CH)  [NB=32, CH=8]

typedef __attribute__((ext_vector_type(8))) __bf16 bf16x8;
typedef __attribute__((ext_vector_type(4))) float  floatx4;
typedef __attribute__((ext_vector_type(8))) unsigned short ushort8;

typedef const __attribute__((address_space(1))) void* gas_ptr;
typedef __attribute__((address_space(3))) void*       las_ptr;

__device__ __forceinline__ unsigned short f32_to_bf16_rne(float f) {
    unsigned u = __builtin_bit_cast(unsigned, f);
    unsigned r = u + 0x7fffu + ((u >> 16) & 1u);
    return (unsigned short)(r >> 16);
}

// --- A: fp32 -> bf16 row-major; skip strictly-lower 128-blocks (never read) ---
__global__ void conv_a_kernel(const float* __restrict__ A,
                              unsigned short* __restrict__ Ab) {
    const int bid = blockIdx.x;
    const int row = bid >> 2;            // one quarter-row (1024 elems) per wg
    const int k0  = (bid & 3) * 1024;
    const int rb  = row >> 7;            // 128-block row
    if (((k0 >> 7) + 8) <= rb) return;   // all 8 k-blocks strictly below diag
    const int idx = row * N + k0 + threadIdx.x * 4;
    const float4 v = *(const float4*)(A + idx);
    ushort4 o;
    o.x = f32_to_bf16_rne(v.x);
    o.y = f32_to_bf16_rne(v.y);
    o.z = f32_to_bf16_rne(v.z);
    o.w = f32_to_bf16_rne(v.w);
    *(ushort4*)(Ab + idx) = o;
}

// --- B: fp32 -> bf16 transposed (Bt[j][k] = B[k][j]); 64x64 LDS transpose.
//     Skip Bt 128-blocks with kb128 > jb128 (never read). ---
__global__ void conv_bt_kernel(const float* __restrict__ B,
                               unsigned short* __restrict__ Bt) {
    __shared__ float tile[64][65];
    const int jb = blockIdx.x;           // Bt row block (B column block), 64-wide
    const int kb = blockIdx.y;           // Bt col block (B row block), 64-wide
    if ((kb >> 1) > (jb >> 1)) return;
    const int j0 = jb * 64, k0 = kb * 64;
    const int t  = threadIdx.x;          // 0..255
    {
        const int kl = t >> 2;           // row of B within tile
        const int j4 = (t & 3) * 16;     // 16 consecutive j per thread
        const float* src = B + (size_t)(k0 + kl) * N + j0 + j4;
        const float4 v0 = ((const float4*)src)[0];
        const float4 v1 = ((const float4*)src)[1];
        const float4 v2 = ((const float4*)src)[2];
        const float4 v3 = ((const float4*)src)[3];
        float* dst = &tile[kl][j4];
        dst[0]=v0.x; dst[1]=v0.y; dst[2]=v0.z; dst[3]=v0.w;
        dst[4]=v1.x; dst[5]=v1.y; dst[6]=v1.z; dst[7]=v1.w;
        dst[8]=v2.x; dst[9]=v2.y; dst[10]=v2.z; dst[11]=v2.w;
        dst[12]=v3.x; dst[13]=v3.y; dst[14]=v3.z; dst[15]=v3.w;
    }
    __syncthreads();
    {
        const int jl = t >> 2;           // row of Bt within tile
        const int k4 = (t & 3) * 16;     // 16 consecutive k per thread
        ushort8 o0, o1;
        #pragma unroll
        for (int i = 0; i < 8; ++i) o0[i] = f32_to_bf16_rne(tile[k4 + i][jl]);
        #pragma unroll
        for (int i = 0; i < 8; ++i) o1[i] = f32_to_bf16_rne(tile[k4 + 8 + i][jl]);
        unsigned short* dst = Bt + (size_t)(j0 + jl) * N + k0 + k4;
        ((ushort8*)dst)[0] = o0;
        ((ushort8*)dst)[1] = o1;
    }
}

// --- split-K triangular-blocked bf16 MFMA GEMM, 2 BK-steps per barrier ---
__global__ __launch_bounds__(256)
void trimm_kernel(const unsigned short* __restrict__ Ab,
                  const unsigned short* __restrict__ Bt,
                  float* __restrict__ C) {
    __shared__ unsigned short sA[2][BM * BK];   // [buf][row*32+k]
    __shared__ unsigned short sB[2][BM * BK];

    // ---- decode blockIdx -> (tile bi,bj ; K-chunk) ; expensive diagonals first
    int rem = blockIdx.x;
    int d = 0, per = 1;
    for (int dd = NB - 1; dd >= 0; --dd) {
        const int p   = (dd + CH) / CH;          // ceil((dd+1)/CH)
        const int cnt = (NB - dd) * p;
        if (rem < cnt) { d = dd; per = p; break; }
        rem -= cnt;
    }
    const int tile  = rem / per;
    const int chunk = rem - tile * per;
    const int bi = tile, bj = tile + d;
    const int c    = d + 1;                      // tile cost in K-blocks
    const int base = c / per, extra = c - base * per;
    const int kb0  = bi + chunk * base + (chunk < extra ? chunk : extra);
    const int len  = base + (chunk < extra ? 1 : 0);

    const int tid  = threadIdx.x;
    const int w    = tid >> 6;        // wave 0..3
    const int lane = tid & 63;
    const int quad = lane >> 4;       // 0..3
    const int l15  = lane & 15;

    const int m0 = (w >> 1) * 64;     // wave quadrant within 128x128
    const int n0 = (w & 1) * 64;
    const int row0 = bi * BM;
    const int col0 = bj * BM;

    floatx4 acc[4][4] = {};

    // staging: 8 wave-chunks of 1KB per tile; wave w does chunks 2w, 2w+1
    const int srow = lane >> 2;        // 0..15 row within chunk
    const int skk  = (lane & 3) * 8;   // k element offset (8 bf16 = 16B)
    const int q0 = w * 2, q1 = w * 2 + 1;
    const int r0 = q0 * 16 + srow, r1 = q1 * 16 + srow;

    const unsigned short* gA0 = Ab + (size_t)(row0 + r0) * N + kb0 * BM + skk;
    const unsigned short* gA1 = Ab + (size_t)(row0 + r1) * N + kb0 * BM + skk;
    const unsigned short* gB0 = Bt + (size_t)(col0 + r0) * N + kb0 * BM + skk;
    const unsigned short* gB1 = Bt + (size_t)(col0 + r1) * N + kb0 * BM + skk;

    const int ns2 = len * 2;           // pairs of BK-steps
    for (int s2 = 0; s2 < ns2; ++s2) {
        // stage both buffers, one drain
        __builtin_amdgcn_global_load_lds((gas_ptr)gA0, (las_ptr)&sA[0][q0 * 512], 16, 0, 0);
        __builtin_amdgcn_global_load_lds((gas_ptr)gA1, (las_ptr)&sA[0][q1 * 512], 16, 0, 0);
        __builtin_amdgcn_global_load_lds((gas_ptr)gB0, (las_ptr)&sB[0][q0 * 512], 16, 0, 0);
        __builtin_amdgcn_global_load_lds((gas_ptr)gB1, (las_ptr)&sB[0][q1 * 512], 16, 0, 0);
        __builtin_amdgcn_global_load_lds((gas_ptr)(gA0 + BK), (las_ptr)&sA[1][q0 * 512], 16, 0, 0);
        __builtin_amdgcn_global_load_lds((gas_ptr)(gA1 + BK), (las_ptr)&sA[1][q1 * 512], 16, 0, 0);
        __builtin_amdgcn_global_load_lds((gas_ptr)(gB0 + BK), (las_ptr)&sB[1][q0 * 512], 16, 0, 0);
        __builtin_amdgcn_global_load_lds((gas_ptr)(gB1 + BK), (las_ptr)&sB[1][q1 * 512], 16, 0, 0);
        gA0 += 2 * BK; gA1 += 2 * BK; gB0 += 2 * BK; gB1 += 2 * BK;
        __syncthreads();

        #pragma unroll
        for (int h = 0; h < 2; ++h) {
            bf16x8 af[4], bfr[4];
            #pragma unroll
            for (int t = 0; t < 4; ++t) {
                af[t]  = *(const bf16x8*)&sA[h][(m0 + t * 16 + l15) * BK + quad * 8];
                bfr[t] = *(const bf16x8*)&sB[h][(n0 + t * 16 + l15) * BK + quad * 8];
            }
            #pragma unroll
            for (int tm = 0; tm < 4; ++tm)
                #pragma unroll
                for (int tn = 0; tn < 4; ++tn)
                    acc[tm][tn] = __builtin_amdgcn_mfma_f32_16x16x32_bf16(
                        af[tm], bfr[tn], acc[tm][tn], 0, 0, 0);
        }
        __syncthreads();
    }

    // ---- epilogue. C/D layout: col=lane&15, row=quad*4+r.
    #pragma unroll
    for (int tm = 0; tm < 4; ++tm) {
        const int grow_base = row0 + m0 + tm * 16 + quad * 4;
        #pragma unroll
        for (int tn = 0; tn < 4; ++tn) {
            const int gcol = col0 + n0 + tn * 16 + l15;
            #pragma unroll
            for (int r = 0; r < 4; ++r) {
                const int grow = grow_base + r;
                float* p = C + (size_t)grow * N + gcol;
                const float v = acc[tm][tn][r];
                if (per > 1) {
                    atomicAdd(p, v);
                } else if (d != 0) {
                    *p = v;
                } else if (gcol >= grow) {
                    *p = v;
                }
            }
        }
    }
}

extern "C" void kernel_launch(void* const* d_in, const int* in_sizes, int n_in,
                              void* d_out, int out_size, void* d_ws, size_t ws_size,
                              hipStream_t stream) {
    const float* A = (const float*)d_in[0];
    const float* B = (const float*)d_in[1];
    float* C = (float*)d_out;

    // workspace: A_bf16 (32 MiB) | Bt_bf16 (32 MiB)
    unsigned short* Ab = (unsigned short*)d_ws;
    unsigned short* Bt = Ab + (size_t)N * N;

    hipMemsetAsync(d_out, 0, (size_t)N * N * sizeof(float), stream);
    conv_a_kernel<<<dim3(N * 4), dim3(256), 0, stream>>>(A, Ab);
    conv_bt_kernel<<<dim3(N / 64, N / 64), dim3(256), 0, stream>>>(B, Bt);
    trimm_kernel<<<dim3(NWG), dim3(256), 0, stream>>>(Ab, Bt, C);
}

// Round 4
// 242.959 us; speedup vs baseline: 1.1142x; 1.0033x over previous
//
#include <hip/hip_runtime.h>

// C = triu(A @ B), A,B upper-triangular fp32 4096x4096.
// R4: (1) trimm K-loop restructured to register staging: global_load->VGPR
//     prefetch for step s+1 issued after barrier(s), R->LDS ds_write, ONE
//     barrier/step (lgkm-only drain; loads stay in flight across barriers --
//     the AITER pattern; global_load_lds's vmcnt(0)-at-barrier drain is gone).
// (2) conv_a + conv_bt + memset fused into one prep kernel; C zeroed only
//     where needed (strictly-lower + atomic tiles); diagonal epilogue stores 0.

#define N   4096
#define NB  32      // N / BM
#define BM  128
#define BK  32
#define CH  8       // K-blocks (128 wide) per chunk
#define NWG 1000    // sum over d of (NB-d)*ceil((d+1)/CH)  [NB=32, CH=8]

typedef __attribute__((ext_vector_type(8))) __bf16 bf16x8;
typedef __attribute__((ext_vector_type(4))) float  floatx4;
typedef __attribute__((ext_vector_type(8))) unsigned short ushort8;

__device__ __forceinline__ unsigned short f32_to_bf16_rne(float f) {
    unsigned u = __builtin_bit_cast(unsigned, f);
    unsigned r = u + 0x7fffu + ((u >> 16) & 1u);
    return (unsigned short)(r >> 16);
}

// --- fused prep: A->bf16 (upper blocks), B->bf16 transposed (needed blocks),
//     zero C where trimm won't plain-store (strictly-lower + atomic tiles) ---
__global__ __launch_bounds__(256)
void prep_kernel(const float* __restrict__ A, const float* __restrict__ B,
                 unsigned short* __restrict__ Ab, unsigned short* __restrict__ Bt,
                 float* __restrict__ C) {
    __shared__ float tile[64][65];
    const int bx = blockIdx.x, by = blockIdx.y;      // 64-granule col/row
    const int x0 = bx * 64, y0 = by * 64;
    const int xb = bx >> 1, yb = by >> 1;            // 128-blocks
    const int t  = threadIdx.x;
    const int tr = t >> 2, tc = (t & 3) * 16;        // 64x(16/thread)

    // A: rows y0.., k-cols x0..; read iff k-block >= row-block
    if (xb >= yb) {
        const float* src = A + (size_t)(y0 + tr) * N + x0 + tc;
        const float4 v0 = ((const float4*)src)[0];
        const float4 v1 = ((const float4*)src)[1];
        const float4 v2 = ((const float4*)src)[2];
        const float4 v3 = ((const float4*)src)[3];
        ushort8 o0, o1;
        o0[0]=f32_to_bf16_rne(v0.x); o0[1]=f32_to_bf16_rne(v0.y);
        o0[2]=f32_to_bf16_rne(v0.z); o0[3]=f32_to_bf16_rne(v0.w);
        o0[4]=f32_to_bf16_rne(v1.x); o0[5]=f32_to_bf16_rne(v1.y);
        o0[6]=f32_to_bf16_rne(v1.z); o0[7]=f32_to_bf16_rne(v1.w);
        o1[0]=f32_to_bf16_rne(v2.x); o1[1]=f32_to_bf16_rne(v2.y);
        o1[2]=f32_to_bf16_rne(v2.z); o1[3]=f32_to_bf16_rne(v2.w);
        o1[4]=f32_to_bf16_rne(v3.x); o1[5]=f32_to_bf16_rne(v3.y);
        o1[6]=f32_to_bf16_rne(v3.z); o1[7]=f32_to_bf16_rne(v3.w);
        unsigned short* dst = Ab + (size_t)(y0 + tr) * N + x0 + tc;
        ((ushort8*)dst)[0] = o0;
        ((ushort8*)dst)[1] = o1;
    }
    // Bt[j][k]=B[k][j]: j rows y0.., k cols x0..; needed iff k-block <= j-block
    if (xb <= yb) {
        const float* src = B + (size_t)(x0 + tr) * N + y0 + tc;   // B[k][j]
        const float4 v0 = ((const float4*)src)[0];
        const float4 v1 = ((const float4*)src)[1];
        const float4 v2 = ((const float4*)src)[2];
        const float4 v3 = ((const float4*)src)[3];
        float* d = &tile[tr][tc];
        d[0]=v0.x; d[1]=v0.y; d[2]=v0.z; d[3]=v0.w;
        d[4]=v1.x; d[5]=v1.y; d[6]=v1.z; d[7]=v1.w;
        d[8]=v2.x; d[9]=v2.y; d[10]=v2.z; d[11]=v2.w;
        d[12]=v3.x; d[13]=v3.y; d[14]=v3.z; d[15]=v3.w;
        __syncthreads();
        ushort8 o0, o1;
        #pragma unroll
        for (int i = 0; i < 8; ++i) o0[i] = f32_to_bf16_rne(tile[tc + i][tr]);
        #pragma unroll
        for (int i = 0; i < 8; ++i) o1[i] = f32_to_bf16_rne(tile[tc + 8 + i][tr]);
        unsigned short* dst = Bt + (size_t)(y0 + tr) * N + x0 + tc;
        ((ushort8*)dst)[0] = o0;
        ((ushort8*)dst)[1] = o1;
    }
    // C zeros: strictly-lower 128-blocks, and atomic tiles (d>=CH)
    if (xb < yb || (xb - yb) >= CH) {
        float4 z = {0.f, 0.f, 0.f, 0.f};
        float* dst = C + (size_t)(y0 + tr) * N + x0 + tc;
        ((float4*)dst)[0] = z; ((float4*)dst)[1] = z;
        ((float4*)dst)[2] = z; ((float4*)dst)[3] = z;
    }
}

// --- split-K triangular MFMA GEMM, register-staged pipeline ---
__global__ __launch_bounds__(256)
void trimm_kernel(const unsigned short* __restrict__ Ab,
                  const unsigned short* __restrict__ Bt,
                  float* __restrict__ C) {
    __shared__ unsigned short sA[2][BM * BK];   // [buf][row*32+k]
    __shared__ unsigned short sB[2][BM * BK];

    // ---- decode blockIdx -> (tile bi,bj ; K-chunk); expensive diagonals first
    int rem = blockIdx.x;
    int d = 0, per = 1;
    for (int dd = NB - 1; dd >= 0; --dd) {
        const int p   = (dd + CH) / CH;          // ceil((dd+1)/CH)
        const int cnt = (NB - dd) * p;
        if (rem < cnt) { d = dd; per = p; break; }
        rem -= cnt;
    }
    const int tile  = rem / per;
    const int chunk = rem - tile * per;
    const int bi = tile, bj = tile + d;
    const int c    = d + 1;
    const int base = c / per, extra = c - base * per;
    const int kb0  = bi + chunk * base + (chunk < extra ? chunk : extra);
    const int len  = base + (chunk < extra ? 1 : 0);

    const int tid  = threadIdx.x;
    const int w    = tid >> 6;
    const int lane = tid & 63;
    const int quad = lane >> 4;
    const int l15  = lane & 15;

    const int m0 = (w >> 1) * 64;
    const int n0 = (w & 1) * 64;
    const int row0 = bi * BM;
    const int col0 = bj * BM;

    floatx4 acc[4][4] = {};

    // staging map: wave w stages rows [32w,32w+32) of each tile;
    // lane -> row q*16+srow, k-seg skk (8 bf16 = 16B)
    const int srow = lane >> 2;
    const int skk  = (lane & 3) * 8;
    const int q0 = w * 2, q1 = w * 2 + 1;
    const int r0 = q0 * 16 + srow, r1 = q1 * 16 + srow;
    const int lofs0 = q0 * 512 + srow * 32 + skk;
    const int lofs1 = q1 * 512 + srow * 32 + skk;

    const unsigned short* gA0 = Ab + (size_t)(row0 + r0) * N + kb0 * BM + skk;
    const unsigned short* gA1 = Ab + (size_t)(row0 + r1) * N + kb0 * BM + skk;
    const unsigned short* gB0 = Bt + (size_t)(col0 + r0) * N + kb0 * BM + skk;
    const unsigned short* gB1 = Bt + (size_t)(col0 + r1) * N + kb0 * BM + skk;

    const int ns = len * 4;            // BK-steps

    // prologue: load step 0 into regs
    ushort8 aR0 = *(const ushort8*)gA0;  gA0 += BK;
    ushort8 aR1 = *(const ushort8*)gA1;  gA1 += BK;
    ushort8 bR0 = *(const ushort8*)gB0;  gB0 += BK;
    ushort8 bR1 = *(const ushort8*)gB1;  gB1 += BK;

    for (int s = 0; s < ns; ++s) {
        const int buf = s & 1;
        // R -> LDS (vmcnt wait lands here, not at the barrier)
        *(ushort8*)&sA[buf][lofs0] = aR0;
        *(ushort8*)&sA[buf][lofs1] = aR1;
        *(ushort8*)&sB[buf][lofs0] = bR0;
        *(ushort8*)&sB[buf][lofs1] = bR1;
        __syncthreads();
        // prefetch step s+1 (stays in flight across next barrier)
        if (s + 1 < ns) {
            aR0 = *(const ushort8*)gA0;  gA0 += BK;
            aR1 = *(const ushort8*)gA1;  gA1 += BK;
            bR0 = *(const ushort8*)gB0;  gB0 += BK;
            bR1 = *(const ushort8*)gB1;  gB1 += BK;
        }
        // LDS -> frags -> MFMA
        bf16x8 af[4], bfr[4];
        #pragma unroll
        for (int t = 0; t < 4; ++t) {
            af[t]  = *(const bf16x8*)&sA[buf][(m0 + t * 16 + l15) * BK + quad * 8];
            bfr[t] = *(const bf16x8*)&sB[buf][(n0 + t * 16 + l15) * BK + quad * 8];
        }
        #pragma unroll
        for (int tm = 0; tm < 4; ++tm)
            #pragma unroll
            for (int tn = 0; tn < 4; ++tn)
                acc[tm][tn] = __builtin_amdgcn_mfma_f32_16x16x32_bf16(
                    af[tm], bfr[tn], acc[tm][tn], 0, 0, 0);
        // no second barrier: double buffer + next iter's barrier covers WAR
    }

    // ---- epilogue. C/D layout: col=lane&15, row=quad*4+r.
    #pragma unroll
    for (int tm = 0; tm < 4; ++tm) {
        const int grow_base = row0 + m0 + tm * 16 + quad * 4;
        #pragma unroll
        for (int tn = 0; tn < 4; ++tn) {
            const int gcol = col0 + n0 + tn * 16 + l15;
            #pragma unroll
            for (int r = 0; r < 4; ++r) {
                const int grow = grow_base + r;
                float* p = C + (size_t)grow * N + gcol;
                const float v = acc[tm][tn][r];
                if (per > 1) {
                    atomicAdd(p, v);           // tile pre-zeroed by prep
                } else if (d != 0) {
                    *p = v;                    // sole writer, full block
                } else {
                    *p = (gcol >= grow) ? v : 0.0f;   // diagonal block
                }
            }
        }
    }
}

extern "C" void kernel_launch(void* const* d_in, const int* in_sizes, int n_in,
                              void* d_out, int out_size, void* d_ws, size_t ws_size,
                              hipStream_t stream) {
    const float* A = (const float*)d_in[0];
    const float* B = (const float*)d_in[1];
    float* C = (float*)d_out;

    unsigned short* Ab = (unsigned short*)d_ws;              // 32 MiB
    unsigned short* Bt = Ab + (size_t)N * N;                 // 32 MiB

    prep_kernel<<<dim3(N / 64, N / 64), dim3(256), 0, stream>>>(A, B, Ab, Bt, C);
    trimm_kernel<<<dim3(NWG), dim3(256), 0, stream>>>(Ab, Bt, C);
}

// Round 5
// 234.723 us; speedup vs baseline: 1.1533x; 1.0351x over previous
//
#include <hip/hip_runtime.h>

// C = triu(A @ B), A,B upper-triangular fp32 4096x4096.
// R5: trimm phases are K=64 (32 MFMA/wave per barrier, 2x R3, 4x R4),
// register-staged (loads for phase p+1 in flight across barrier p),
// double-buffered LDS with +8-ushort row padding (RS=72 -> conflict-free
// bank walk), one barrier per phase, tail-peeled. Split-K CH=8 grid,
// fused prep (bf16 convert A / transpose-convert B / partial C zero).

#define N   4096
#define NB  32      // N / BM
#define BM  128
#define PK  64      // K per pipeline phase
#define CH  8       // K-blocks (128 wide) per chunk
#define NWG 1000    // sum over d of (NB-d)*ceil((d+1)/CH)  [NB=32, CH=8]
#define RS  72      // LDS row stride in ushorts (64 + 8 pad)

typedef __attribute__((ext_vector_type(8))) __bf16 bf16x8;
typedef __attribute__((ext_vector_type(4))) float  floatx4;
typedef __attribute__((ext_vector_type(8))) unsigned short ushort8;

__device__ __forceinline__ unsigned short f32_to_bf16_rne(float f) {
    unsigned u = __builtin_bit_cast(unsigned, f);
    unsigned r = u + 0x7fffu + ((u >> 16) & 1u);
    return (unsigned short)(r >> 16);
}

// --- fused prep: A->bf16 (upper blocks), B->bf16 transposed (needed blocks),
//     zero C where trimm won't plain-store (strictly-lower + atomic tiles) ---
__global__ __launch_bounds__(256)
void prep_kernel(const float* __restrict__ A, const float* __restrict__ B,
                 unsigned short* __restrict__ Ab, unsigned short* __restrict__ Bt,
                 float* __restrict__ C) {
    __shared__ float tile[64][65];
    const int bx = blockIdx.x, by = blockIdx.y;      // 64-granule col/row
    const int x0 = bx * 64, y0 = by * 64;
    const int xb = bx >> 1, yb = by >> 1;            // 128-blocks
    const int t  = threadIdx.x;
    const int tr = t >> 2, tc = (t & 3) * 16;        // 64x(16/thread)

    // A: rows y0.., k-cols x0..; read iff k-block >= row-block
    if (xb >= yb) {
        const float* src = A + (size_t)(y0 + tr) * N + x0 + tc;
        const float4 v0 = ((const float4*)src)[0];
        const float4 v1 = ((const float4*)src)[1];
        const float4 v2 = ((const float4*)src)[2];
        const float4 v3 = ((const float4*)src)[3];
        ushort8 o0, o1;
        o0[0]=f32_to_bf16_rne(v0.x); o0[1]=f32_to_bf16_rne(v0.y);
        o0[2]=f32_to_bf16_rne(v0.z); o0[3]=f32_to_bf16_rne(v0.w);
        o0[4]=f32_to_bf16_rne(v1.x); o0[5]=f32_to_bf16_rne(v1.y);
        o0[6]=f32_to_bf16_rne(v1.z); o0[7]=f32_to_bf16_rne(v1.w);
        o1[0]=f32_to_bf16_rne(v2.x); o1[1]=f32_to_bf16_rne(v2.y);
        o1[2]=f32_to_bf16_rne(v2.z); o1[3]=f32_to_bf16_rne(v2.w);
        o1[4]=f32_to_bf16_rne(v3.x); o1[5]=f32_to_bf16_rne(v3.y);
        o1[6]=f32_to_bf16_rne(v3.z); o1[7]=f32_to_bf16_rne(v3.w);
        unsigned short* dst = Ab + (size_t)(y0 + tr) * N + x0 + tc;
        ((ushort8*)dst)[0] = o0;
        ((ushort8*)dst)[1] = o1;
    }
    // Bt[j][k]=B[k][j]: j rows y0.., k cols x0..; needed iff k-block <= j-block
    if (xb <= yb) {
        const float* src = B + (size_t)(x0 + tr) * N + y0 + tc;   // B[k][j]
        const float4 v0 = ((const float4*)src)[0];
        const float4 v1 = ((const float4*)src)[1];
        const float4 v2 = ((const float4*)src)[2];
        const float4 v3 = ((const float4*)src)[3];
        float* d = &tile[tr][tc];
        d[0]=v0.x; d[1]=v0.y; d[2]=v0.z; d[3]=v0.w;
        d[4]=v1.x; d[5]=v1.y; d[6]=v1.z; d[7]=v1.w;
        d[8]=v2.x; d[9]=v2.y; d[10]=v2.z; d[11]=v2.w;
        d[12]=v3.x; d[13]=v3.y; d[14]=v3.z; d[15]=v3.w;
        __syncthreads();
        ushort8 o0, o1;
        #pragma unroll
        for (int i = 0; i < 8; ++i) o0[i] = f32_to_bf16_rne(tile[tc + i][tr]);
        #pragma unroll
        for (int i = 0; i < 8; ++i) o1[i] = f32_to_bf16_rne(tile[tc + 8 + i][tr]);
        unsigned short* dst = Bt + (size_t)(y0 + tr) * N + x0 + tc;
        ((ushort8*)dst)[0] = o0;
        ((ushort8*)dst)[1] = o1;
    }
    // C zeros: strictly-lower 128-blocks, and atomic tiles (d>=CH)
    if (xb < yb || (xb - yb) >= CH) {
        float4 z = {0.f, 0.f, 0.f, 0.f};
        float* dst = C + (size_t)(y0 + tr) * N + x0 + tc;
        ((float4*)dst)[0] = z; ((float4*)dst)[1] = z;
        ((float4*)dst)[2] = z; ((float4*)dst)[3] = z;
    }
}

// --- split-K triangular MFMA GEMM, K=64 phases, reg-staged dbuf pipeline ---
__global__ __launch_bounds__(256, 2)
void trimm_kernel(const unsigned short* __restrict__ Ab,
                  const unsigned short* __restrict__ Bt,
                  float* __restrict__ C) {
    __shared__ unsigned short sA[2][BM * RS];   // padded: row stride 72 ushorts
    __shared__ unsigned short sB[2][BM * RS];

    // ---- decode blockIdx -> (tile bi,bj ; K-chunk); expensive diagonals first
    int rem = blockIdx.x;
    int d = 0, per = 1;
    for (int dd = NB - 1; dd >= 0; --dd) {
        const int p   = (dd + CH) / CH;          // ceil((dd+1)/CH)
        const int cnt = (NB - dd) * p;
        if (rem < cnt) { d = dd; per = p; break; }
        rem -= cnt;
    }
    const int tile  = rem / per;
    const int chunk = rem - tile * per;
    const int bi = tile, bj = tile + d;
    const int c    = d + 1;
    const int base = c / per, extra = c - base * per;
    const int kb0  = bi + chunk * base + (chunk < extra ? chunk : extra);
    const int len  = base + (chunk < extra ? 1 : 0);

    const int tid  = threadIdx.x;
    const int w    = tid >> 6;
    const int lane = tid & 63;
    const int quad = lane >> 4;
    const int l15  = lane & 15;

    const int m0 = (w >> 1) * 64;
    const int n0 = (w & 1) * 64;
    const int row0 = bi * BM;
    const int col0 = bj * BM;

    floatx4 acc[4][4] = {};

    // staging map: wave w stages rows [32w, 32w+32); per load instr i (0..3):
    // row = 32w + 8i + (lane>>3), k-seg = (lane&7)*8  (8 rows x 128B each)
    const int srow8 = lane >> 3;
    const int sk    = (lane & 7) * 8;
    int lofs[4];
    const unsigned short* gA[4];
    const unsigned short* gB[4];
    #pragma unroll
    for (int i = 0; i < 4; ++i) {
        const int r = w * 32 + i * 8 + srow8;
        lofs[i] = r * RS + sk;
        gA[i] = Ab + (size_t)(row0 + r) * N + kb0 * BM + sk;
        gB[i] = Bt + (size_t)(col0 + r) * N + kb0 * BM + sk;
    }

    const int np = len * 2;            // K=64 phases (>=2)

    // prologue: phase-0 loads into regs
    ushort8 aR[4], bR[4];
    #pragma unroll
    for (int i = 0; i < 4; ++i) { aR[i] = *(const ushort8*)gA[i]; gA[i] += PK; }
    #pragma unroll
    for (int i = 0; i < 4; ++i) { bR[i] = *(const ushort8*)gB[i]; gB[i] += PK; }

    auto compute_phase = [&](int buf) {
        #pragma unroll
        for (int h = 0; h < 2; ++h) {
            bf16x8 af[4], bfr[4];
            #pragma unroll
            for (int t = 0; t < 4; ++t) {
                af[t]  = *(const bf16x8*)&sA[buf][(m0 + t * 16 + l15) * RS + h * 32 + quad * 8];
                bfr[t] = *(const bf16x8*)&sB[buf][(n0 + t * 16 + l15) * RS + h * 32 + quad * 8];
            }
            #pragma unroll
            for (int tm = 0; tm < 4; ++tm)
                #pragma unroll
                for (int tn = 0; tn < 4; ++tn)
                    acc[tm][tn] = __builtin_amdgcn_mfma_f32_16x16x32_bf16(
                        af[tm], bfr[tn], acc[tm][tn], 0, 0, 0);
        }
    };

    for (int p = 0; p < np - 1; ++p) {
        const int buf = p & 1;
        #pragma unroll
        for (int i = 0; i < 4; ++i) *(ushort8*)&sA[buf][lofs[i]] = aR[i];
        #pragma unroll
        for (int i = 0; i < 4; ++i) *(ushort8*)&sB[buf][lofs[i]] = bR[i];
        __syncthreads();
        // prefetch phase p+1 (in flight across the next barrier)
        #pragma unroll
        for (int i = 0; i < 4; ++i) { aR[i] = *(const ushort8*)gA[i]; gA[i] += PK; }
        #pragma unroll
        for (int i = 0; i < 4; ++i) { bR[i] = *(const ushort8*)gB[i]; gB[i] += PK; }
        compute_phase(buf);
        // no trailing barrier: next phase writes the other buffer; a wave can
        // only re-enter THIS buffer after the next barrier, by which time all
        // waves' reads here are complete (reads precede their barrier arrival)
    }
    {   // tail phase
        const int buf = (np - 1) & 1;
        #pragma unroll
        for (int i = 0; i < 4; ++i) *(ushort8*)&sA[buf][lofs[i]] = aR[i];
        #pragma unroll
        for (int i = 0; i < 4; ++i) *(ushort8*)&sB[buf][lofs[i]] = bR[i];
        __syncthreads();
        compute_phase(buf);
    }

    // ---- epilogue. C/D layout: col=lane&15, row=quad*4+r.
    #pragma unroll
    for (int tm = 0; tm < 4; ++tm) {
        const int grow_base = row0 + m0 + tm * 16 + quad * 4;
        #pragma unroll
        for (int tn = 0; tn < 4; ++tn) {
            const int gcol = col0 + n0 + tn * 16 + l15;
            #pragma unroll
            for (int r = 0; r < 4; ++r) {
                const int grow = grow_base + r;
                float* p = C + (size_t)grow * N + gcol;
                const float v = acc[tm][tn][r];
                if (per > 1) {
                    atomicAdd(p, v);           // tile pre-zeroed by prep
                } else if (d != 0) {
                    *p = v;                    // sole writer, full block
                } else {
                    *p = (gcol >= grow) ? v : 0.0f;   // diagonal block
                }
            }
        }
    }
}

extern "C" void kernel_launch(void* const* d_in, const int* in_sizes, int n_in,
                              void* d_out, int out_size, void* d_ws, size_t ws_size,
                              hipStream_t stream) {
    const float* A = (const float*)d_in[0];
    const float* B = (const float*)d_in[1];
    float* C = (float*)d_out;

    unsigned short* Ab = (unsigned short*)d_ws;              // 32 MiB
    unsigned short* Bt = Ab + (size_t)N * N;                 // 32 MiB

    prep_kernel<<<dim3(N / 64, N / 64), dim3(256), 0, stream>>>(A, B, Ab, Bt, C);
    trimm_kernel<<<dim3(NWG), dim3(256), 0, stream>>>(Ab, Bt, C);
}

// Round 6
// 229.706 us; speedup vs baseline: 1.1785x; 1.0218x over previous
//
#include <hip/hip_runtime.h>

// C = triu(A @ B), A,B upper-triangular fp32 4096x4096.
// R6: NO ATOMICS. Persistent work-list: 512 wgs (2/CU), snake-assigned whole
// tiles (d descending), full-K per tile, plain stores (single writer per C
// element). Per-job K-loop = R5's verified K=64 reg-staged dbuf pipeline
// (loads in flight across barriers, RS=72 padded LDS, 1 barrier/phase).
// prep zeros only strictly-lower 128-blocks; diagonal jobs store 0 below diag.

#define N    4096
#define NB   32      // N / BM
#define BM   128
#define PK   64      // K per pipeline phase
#define NWG  512
#define NJOB 528     // NB*(NB+1)/2 upper tiles
#define RS   72      // LDS row stride in ushorts (64 + 8 pad)

typedef __attribute__((ext_vector_type(8))) __bf16 bf16x8;
typedef __attribute__((ext_vector_type(4))) float  floatx4;
typedef __attribute__((ext_vector_type(8))) unsigned short ushort8;

__device__ __forceinline__ unsigned short f32_to_bf16_rne(float f) {
    unsigned u = __builtin_bit_cast(unsigned, f);
    unsigned r = u + 0x7fffu + ((u >> 16) & 1u);
    return (unsigned short)(r >> 16);
}

// --- fused prep: A->bf16 (upper blocks), B->bf16 transposed (needed blocks),
//     zero C on strictly-lower 128-blocks only ---
__global__ __launch_bounds__(256)
void prep_kernel(const float* __restrict__ A, const float* __restrict__ B,
                 unsigned short* __restrict__ Ab, unsigned short* __restrict__ Bt,
                 float* __restrict__ C) {
    __shared__ float tile[64][65];
    const int bx = blockIdx.x, by = blockIdx.y;      // 64-granule col/row
    const int x0 = bx * 64, y0 = by * 64;
    const int xb = bx >> 1, yb = by >> 1;            // 128-blocks
    const int t  = threadIdx.x;
    const int tr = t >> 2, tc = (t & 3) * 16;        // 64x(16/thread)

    // A: rows y0.., k-cols x0..; needed iff k-block >= row-block
    if (xb >= yb) {
        const float* src = A + (size_t)(y0 + tr) * N + x0 + tc;
        const float4 v0 = ((const float4*)src)[0];
        const float4 v1 = ((const float4*)src)[1];
        const float4 v2 = ((const float4*)src)[2];
        const float4 v3 = ((const float4*)src)[3];
        ushort8 o0, o1;
        o0[0]=f32_to_bf16_rne(v0.x); o0[1]=f32_to_bf16_rne(v0.y);
        o0[2]=f32_to_bf16_rne(v0.z); o0[3]=f32_to_bf16_rne(v0.w);
        o0[4]=f32_to_bf16_rne(v1.x); o0[5]=f32_to_bf16_rne(v1.y);
        o0[6]=f32_to_bf16_rne(v1.z); o0[7]=f32_to_bf16_rne(v1.w);
        o1[0]=f32_to_bf16_rne(v2.x); o1[1]=f32_to_bf16_rne(v2.y);
        o1[2]=f32_to_bf16_rne(v2.z); o1[3]=f32_to_bf16_rne(v2.w);
        o1[4]=f32_to_bf16_rne(v3.x); o1[5]=f32_to_bf16_rne(v3.y);
        o1[6]=f32_to_bf16_rne(v3.z); o1[7]=f32_to_bf16_rne(v3.w);
        unsigned short* dst = Ab + (size_t)(y0 + tr) * N + x0 + tc;
        ((ushort8*)dst)[0] = o0;
        ((ushort8*)dst)[1] = o1;
    }
    // Bt[j][k]=B[k][j]: j rows y0.., k cols x0..; needed iff k-block <= j-block
    if (xb <= yb) {
        const float* src = B + (size_t)(x0 + tr) * N + y0 + tc;   // B[k][j]
        const float4 v0 = ((const float4*)src)[0];
        const float4 v1 = ((const float4*)src)[1];
        const float4 v2 = ((const float4*)src)[2];
        const float4 v3 = ((const float4*)src)[3];
        float* d = &tile[tr][tc];
        d[0]=v0.x; d[1]=v0.y; d[2]=v0.z; d[3]=v0.w;
        d[4]=v1.x; d[5]=v1.y; d[6]=v1.z; d[7]=v1.w;
        d[8]=v2.x; d[9]=v2.y; d[10]=v2.z; d[11]=v2.w;
        d[12]=v3.x; d[13]=v3.y; d[14]=v3.z; d[15]=v3.w;
        __syncthreads();
        ushort8 o0, o1;
        #pragma unroll
        for (int i = 0; i < 8; ++i) o0[i] = f32_to_bf16_rne(tile[tc + i][tr]);
        #pragma unroll
        for (int i = 0; i < 8; ++i) o1[i] = f32_to_bf16_rne(tile[tc + 8 + i][tr]);
        unsigned short* dst = Bt + (size_t)(y0 + tr) * N + x0 + tc;
        ((ushort8*)dst)[0] = o0;
        ((ushort8*)dst)[1] = o1;
    }
    // C zeros: strictly-lower 128-blocks only (diag blocks handled by trimm)
    if (xb < yb) {
        float4 z = {0.f, 0.f, 0.f, 0.f};
        float* dst = C + (size_t)(y0 + tr) * N + x0 + tc;
        ((float4*)dst)[0] = z; ((float4*)dst)[1] = z;
        ((float4*)dst)[2] = z; ((float4*)dst)[3] = z;
    }
}

// --- persistent-workgroup triangular MFMA GEMM, K=64 reg-staged pipeline ---
__global__ __launch_bounds__(256, 2)
void trimm_kernel(const unsigned short* __restrict__ Ab,
                  const unsigned short* __restrict__ Bt,
                  float* __restrict__ C) {
    __shared__ unsigned short sA[2][BM * RS];
    __shared__ unsigned short sB[2][BM * RS];

    const int tid  = threadIdx.x;
    const int w    = tid >> 6;
    const int lane = tid & 63;
    const int quad = lane >> 4;
    const int l15  = lane & 15;

    const int m0 = (w >> 1) * 64;
    const int n0 = (w & 1) * 64;

    // staging map (per wave w, rows [32w,32w+32)): instr i -> row 32w+8i+(lane>>3)
    const int srow8 = lane >> 3;
    const int sk    = (lane & 7) * 8;
    int lofs[4], rr[4];
    #pragma unroll
    for (int i = 0; i < 4; ++i) {
        rr[i]   = w * 32 + i * 8 + srow8;
        lofs[i] = rr[i] * RS + sk;
    }

    // snake job list: pass p -> job p*NWG + (p odd ? NWG-1-b : b)
    for (int p = 0;; ++p) {
        const int idx = p * NWG + ((p & 1) ? (NWG - 1 - (int)blockIdx.x)
                                           : (int)blockIdx.x);
        if (idx >= NJOB) break;

        // decode job -> (d, bi): jobs ordered d=31..0, bi ascending
        int rem = idx, d = NB - 1;
        for (; d >= 0; --d) {
            const int cnt = NB - d;
            if (rem < cnt) break;
            rem -= cnt;
        }
        const int bi = rem, bj = bi + d;
        const int row0 = bi * BM;
        const int col0 = bj * BM;

        floatx4 acc[4][4] = {};

        const unsigned short* gA[4];
        const unsigned short* gB[4];
        #pragma unroll
        for (int i = 0; i < 4; ++i) {
            gA[i] = Ab + (size_t)(row0 + rr[i]) * N + bi * BM + sk;
            gB[i] = Bt + (size_t)(col0 + rr[i]) * N + bi * BM + sk;
        }

        const int np = (d + 1) * 2;    // K=64 phases (>=2)

        ushort8 aR[4], bR[4];
        #pragma unroll
        for (int i = 0; i < 4; ++i) { aR[i] = *(const ushort8*)gA[i]; gA[i] += PK; }
        #pragma unroll
        for (int i = 0; i < 4; ++i) { bR[i] = *(const ushort8*)gB[i]; gB[i] += PK; }

        for (int ph = 0; ph < np - 1; ++ph) {
            const int buf = ph & 1;
            #pragma unroll
            for (int i = 0; i < 4; ++i) *(ushort8*)&sA[buf][lofs[i]] = aR[i];
            #pragma unroll
            for (int i = 0; i < 4; ++i) *(ushort8*)&sB[buf][lofs[i]] = bR[i];
            __syncthreads();
            #pragma unroll
            for (int i = 0; i < 4; ++i) { aR[i] = *(const ushort8*)gA[i]; gA[i] += PK; }
            #pragma unroll
            for (int i = 0; i < 4; ++i) { bR[i] = *(const ushort8*)gB[i]; gB[i] += PK; }
            #pragma unroll
            for (int h = 0; h < 2; ++h) {
                bf16x8 af[4], bfr[4];
                #pragma unroll
                for (int t = 0; t < 4; ++t) {
                    af[t]  = *(const bf16x8*)&sA[buf][(m0 + t * 16 + l15) * RS + h * 32 + quad * 8];
                    bfr[t] = *(const bf16x8*)&sB[buf][(n0 + t * 16 + l15) * RS + h * 32 + quad * 8];
                }
                #pragma unroll
                for (int tm = 0; tm < 4; ++tm)
                    #pragma unroll
                    for (int tn = 0; tn < 4; ++tn)
                        acc[tm][tn] = __builtin_amdgcn_mfma_f32_16x16x32_bf16(
                            af[tm], bfr[tn], acc[tm][tn], 0, 0, 0);
            }
        }
        {   // tail phase
            const int buf = (np - 1) & 1;
            #pragma unroll
            for (int i = 0; i < 4; ++i) *(ushort8*)&sA[buf][lofs[i]] = aR[i];
            #pragma unroll
            for (int i = 0; i < 4; ++i) *(ushort8*)&sB[buf][lofs[i]] = bR[i];
            __syncthreads();
            #pragma unroll
            for (int h = 0; h < 2; ++h) {
                bf16x8 af[4], bfr[4];
                #pragma unroll
                for (int t = 0; t < 4; ++t) {
                    af[t]  = *(const bf16x8*)&sA[buf][(m0 + t * 16 + l15) * RS + h * 32 + quad * 8];
                    bfr[t] = *(const bf16x8*)&sB[buf][(n0 + t * 16 + l15) * RS + h * 32 + quad * 8];
                }
                #pragma unroll
                for (int tm = 0; tm < 4; ++tm)
                    #pragma unroll
                    for (int tn = 0; tn < 4; ++tn)
                        acc[tm][tn] = __builtin_amdgcn_mfma_f32_16x16x32_bf16(
                            af[tm], bfr[tn], acc[tm][tn], 0, 0, 0);
            }
            __syncthreads();   // protect LDS before next job reuses buffers
        }

        // epilogue: plain stores (single writer). C/D layout: col=l15, row=quad*4+r
        #pragma unroll
        for (int tm = 0; tm < 4; ++tm) {
            const int grow_base = row0 + m0 + tm * 16 + quad * 4;
            #pragma unroll
            for (int tn = 0; tn < 4; ++tn) {
                const int gcol = col0 + n0 + tn * 16 + l15;
                #pragma unroll
                for (int r = 0; r < 4; ++r) {
                    const int grow = grow_base + r;
                    const float v = acc[tm][tn][r];
                    if (d != 0) {
                        C[(size_t)grow * N + gcol] = v;
                    } else {
                        C[(size_t)grow * N + gcol] = (gcol >= grow) ? v : 0.0f;
                    }
                }
            }
        }
    }
}

extern "C" void kernel_launch(void* const* d_in, const int* in_sizes, int n_in,
                              void* d_out, int out_size, void* d_ws, size_t ws_size,
                              hipStream_t stream) {
    const float* A = (const float*)d_in[0];
    const float* B = (const float*)d_in[1];
    float* C = (float*)d_out;

    unsigned short* Ab = (unsigned short*)d_ws;              // 32 MiB
    unsigned short* Bt = Ab + (size_t)N * N;                 // 32 MiB

    prep_kernel<<<dim3(N / 64, N / 64), dim3(256), 0, stream>>>(A, B, Ab, Bt, C);
    trimm_kernel<<<dim3(NWG), dim3(256), 0, stream>>>(Ab, Bt, C);
}